// Round 5
// baseline (275.477 us; speedup 1.0000x reference)
//
#include <hip/hip_runtime.h>
#include <cmath>

constexpr int S = 160;
constexpr int BATCH = 4;
constexpr int ZSPLIT = 4;
constexpr int ROWS = S / ZSPLIT;               // 40 rows per block
constexpr int KC = S / 4;                      // 40 float4-chunks per row
constexpr int PSTR = KC + 4;                   // padded part stride (16B aligned)
constexpr int CHUNKS = ROWS * KC;              // 1600 chunks per block
constexpr int TPB = 256;
constexpr int FULL_STEPS = CHUNKS / TPB;       // 6
constexpr int TAIL = CHUNKS - FULL_STEPS * TPB;// 64

__device__ __forceinline__ float sigmoidf_(float x) {
  return 1.0f / (1.0f + expf(-x));
}

// wf[b][h][t] = (mask[b][t][h] != 0 && t != h) ? 1 : 0   (byte)
__global__ void prep_wf(const int* __restrict__ mask, unsigned char* __restrict__ wf) {
  int i = blockIdx.x * blockDim.x + threadIdx.x;
  if (i >= BATCH * S * S) return;
  int t = i % S;
  int bh = i / S;
  int h = bh % S;
  int b = bh / S;
  wf[i] = (mask[(b * S + t) * S + h] != 0 && t != h) ? 1 : 0;
}

// One block per (b, m, z). 256 threads stream 40 contiguous rows
// (1600 float4 chunks) of s_sib/s_cop/s_grd/wf with 2-step register batching;
// masked partials go to padded LDS; threads 0..39 reduce one row each.
template <bool FIRST, bool LAST>
__global__ __launch_bounds__(TPB, 8) void mfvi_iter(
    const float* __restrict__ s_edge,   // [b][m][h]
    const float* __restrict__ s_sib,    // [b][m][h][t]
    const float* __restrict__ s_cop,
    const float* __restrict__ s_grd,
    const int* __restrict__ mask,       // [b][x][y]
    const unsigned char* __restrict__ wf,  // [b][h][t]
    const float* __restrict__ q1_in,    // [b][x][y] = q1[x,y,b]
    float* __restrict__ q1_out,
    float* __restrict__ outp) {         // [b][m][h][2]
  const int m = blockIdx.x;
  const int b = blockIdx.y;
  const int z = blockIdx.z;
  const int tid = threadIdx.x;

  __shared__ __align__(16) float part[ROWS * PSTR];  // 7040 B
  __shared__ __align__(16) float colm[S];            // q1[t, m, b]
  __shared__ __align__(16) float rowm[S];            // q1[m, t, b]
  __shared__ float sef[ROWS];
  __shared__ float pmf[ROWS];

  const float* G = q1_in + (size_t)b * S * S;
  const size_t bm = (size_t)b * S + m;
  const int h0 = z * ROWS;

  if (tid < S) {
    if (!FIRST) {
      colm[tid] = G[tid * S + m];
      rowm[tid] = G[m * S + tid];
    }
    if (tid < ROWS) {
      sef[tid] = s_edge[bm * S + h0 + tid];
      pmf[tid] = (mask[bm * S + h0 + tid] != 0) ? 1.0f : 0.0f;
    }
  }
  __syncthreads();

  const size_t blk = (bm * S + h0) * (size_t)S;
  const float4* SS = (const float4*)(s_sib + blk);
  const float4* CC = (const float4*)(s_cop + blk);
  const float4* GG = (const float4*)(s_grd + blk);
  const float4* QQ = (const float4*)(G + h0 * S);
  const unsigned* WF = (const unsigned*)(wf + ((size_t)b * S + h0) * S);
  const int msel = m >> 2;
  const unsigned mclr = ~(255u << ((m & 3) * 8));

  auto compute = [&](int c, unsigned wu, const float4& s, const float4& cv,
                     const float4& g) {
    unsigned uc = (unsigned)c;
    unsigned r = uc / (unsigned)KC;
    unsigned k = uc - r * (unsigned)KC;
    if ((int)k == msel) wu &= mclr;
    float w0 = (float)(wu & 255u);
    float w1 = (float)((wu >> 8) & 255u);
    float w2 = (float)((wu >> 16) & 255u);
    float w3 = (float)(wu >> 24);
    float p;
    if (FIRST) {  // q1 == 0.5 everywhere; 0.5 factor applied in epilogue
      float t0 = s.x + cv.x + g.x;
      float t1 = s.y + cv.y + g.y;
      float t2 = s.z + cv.z + g.z;
      float t3 = s.w + cv.w + g.w;
      p = fmaf(w0, t0, fmaf(w1, t1, fmaf(w2, t2, w3 * t3)));
    } else {
      float4 q = QQ[c];                       // L2/L3-warm, short latency
      float4 cm = ((const float4*)colm)[k];
      float4 rm = ((const float4*)rowm)[k];
      float t0 = fmaf(q.x, s.x, fmaf(cm.x, cv.x, rm.x * g.x));
      float t1 = fmaf(q.y, s.y, fmaf(cm.y, cv.y, rm.y * g.y));
      float t2 = fmaf(q.z, s.z, fmaf(cm.z, cv.z, rm.z * g.z));
      float t3 = fmaf(q.w, s.w, fmaf(cm.w, cv.w, rm.w * g.w));
      p = fmaf(w0, t0, fmaf(w1, t1, fmaf(w2, t2, w3 * t3)));
    }
    part[r * PSTR + k] = p;
  };

#pragma unroll
  for (int sp = 0; sp < FULL_STEPS / 2; ++sp) {
    const int c0 = (2 * sp) * TPB + tid;
    const int c1 = c0 + TPB;
    // issue all 8 long-latency loads back-to-back (graduated vmcnt waits)
    unsigned wu0 = WF[c0];
    unsigned wu1 = WF[c1];
    float4 s0 = SS[c0];
    float4 s1 = SS[c1];
    float4 cv0 = CC[c0];
    float4 cv1 = CC[c1];
    float4 g0 = GG[c0];
    float4 g1 = GG[c1];
    compute(c0, wu0, s0, cv0, g0);
    compute(c1, wu1, s1, cv1, g1);
  }
  {  // tail: 64 chunks
    if (tid < TAIL) {
      const int c = FULL_STEPS * TPB + tid;
      compute(c, WF[c], SS[c], CC[c], GG[c]);
    }
  }
  __syncthreads();

  if (tid < ROWS) {
    const float4* pr = (const float4*)(part + tid * PSTR);
    float4 a = pr[0];
#pragma unroll
    for (int i = 1; i < KC / 4; ++i) {
      float4 v = pr[i];
      a.x += v.x; a.y += v.y; a.z += v.z; a.w += v.w;
    }
    float acc = (a.x + a.y) + (a.z + a.w);
    const int h = h0 + tid;
    const float qv = fmaf(pmf[tid], FIRST ? 0.5f * acc : acc, sef[tid]);
    if (!LAST) {
      q1_out[((size_t)b * S + h) * S + m] = sigmoidf_(qv);
    } else {
      float2 o;
      o.x = sigmoidf_(-qv);
      o.y = sigmoidf_(qv);
      ((float2*)outp)[bm * S + h] = o;
    }
  }
}

extern "C" void kernel_launch(void* const* d_in, const int* in_sizes, int n_in,
                              void* d_out, int out_size, void* d_ws, size_t ws_size,
                              hipStream_t stream) {
  const float* s_edge = (const float*)d_in[0];
  const float* s_sib = (const float*)d_in[1];
  const float* s_cop = (const float*)d_in[2];
  const float* s_grd = (const float*)d_in[3];
  const int* mask = (const int*)d_in[4];
  float* outp = (float*)d_out;

  const int qn = BATCH * S * S;
  float* q1A = (float*)d_ws;
  float* q1B = q1A + qn;
  unsigned char* wf = (unsigned char*)(q1B + qn);  // qn bytes

  prep_wf<<<(qn + 255) / 256, 256, 0, stream>>>(mask, wf);

  dim3 grid(S, BATCH, ZSPLIT);
  // iter 1: q1 == 0.5 (analytic) -> q1B
  mfvi_iter<true, false><<<grid, TPB, 0, stream>>>(
      s_edge, s_sib, s_cop, s_grd, mask, wf, q1A, q1B, nullptr);
  // iter 2: q1B -> q1A
  mfvi_iter<false, false><<<grid, TPB, 0, stream>>>(
      s_edge, s_sib, s_cop, s_grd, mask, wf, q1B, q1A, nullptr);
  // iter 3: q1A -> out (probabilities)
  mfvi_iter<false, true><<<grid, TPB, 0, stream>>>(
      s_edge, s_sib, s_cop, s_grd, mask, wf, q1A, nullptr, outp);
}